// Round 15
// baseline (23.133 us; speedup 1.0000x reference)
//
#include <hip/hip_runtime.h>
#include <cmath>
#include <cstdint>

#define LLEN 131072
#define IIRL 16384
#define CHUNK 16384           // == IIRL: window = exactly 1 prev chunk
#define NBLK (LLEN / CHUNK)   // 8 chunks per row
#define TPB 1024
#define NW (TPB / 64)         // 16 waves; 1024 elements per wave segment
// layout within a wave segment: elem i = 4*(64*q + lane) + m, q,m in [0,4)
// -> every float4 load/store is lane-contiguous (64 lanes x 16B = 1KiB)

typedef float floatx4 __attribute__((ext_vector_type(4)));

__device__ __forceinline__ float powiu(float b, unsigned e) {
    float r = 1.0f;
    while (e) { if (e & 1u) r *= b; b *= b; e >>= 1; }
    return r;
}

// native base-2 transcendentals (v_exp_f32 / v_log_f32)
__device__ __forceinline__ float exp2_hw(float x) { return __builtin_amdgcn_exp2f(x); }
__device__ __forceinline__ float log2_hw(float x) { return __builtin_amdgcn_logf(x); }

// ---------------------------------------------------------------------------
// Single-read compressor with depth-1 decoupled lookback.
// carry(c) = env[start-1] = T(c-1) = RAW weighted total of chunk c-1 (the
// truncated FIR window is exactly one chunk) — and T(c-1) is precisely the
// block total that block c-1 computes from its own scan. Publish it (release,
// device scope) right after the LDS combine; consumer spins (1 lane, 1 addr,
// depth 1; producer publishes ~60% into its runtime; 256 blocks = 1/CU all
// co-resident; publish precedes consume => deadlock-free).
// Rare alpha>0.9947 path (A16K!=0, needs prev data for the b-tail anyway)
// falls back to local prev-chunk read — block-uniform branch, exact.
// gain = (1+u)^coef, u = exp2(knee*log2(env+eps) + C0), C0 = -knee*T*log2e
// env[t] = a*env[t-1] + (1-a)*(ls[t] - a^16384*ls[t-16384]), ls = mean_c(x^2)
// ---------------------------------------------------------------------------
__global__ __launch_bounds__(TPB) void k_fused(
    const float* __restrict__ x, const float* __restrict__ za,
    const float* __restrict__ lt, const float* __restrict__ lr,
    const float* __restrict__ lk, uint64_t* __restrict__ P,
    float* __restrict__ out)
{
    // XCD-aware bijective swizzle: consecutive chunks of a row -> same XCD.
    const int d     = blockIdx.y * gridDim.x + blockIdx.x;
    const int per   = (gridDim.x * gridDim.y) >> 3;   // total % 8 == 0
    const int w     = (d & 7) * per + (d >> 3);
    const int chunk = w % NBLK, n = w / NBLK;

    const int tid = threadIdx.x, lane = tid & 63, wid = tid >> 6;

    const float alpha = 1.0f / (1.0f + __expf(-za[n]));
    const float omah  = 0.5f * (1.0f - alpha);
    const float A16K  = powiu(alpha, IIRL);   // 0 unless alpha > 0.9947
    const float LOG2E = 1.4426950408889634f;
    const float Tthr  = lt[n] - 6.0f;
    const float ratio = 1.0f + __expf(lr[n]);
    const float knee  = __expf(lk[n] - 1.0f);
    const float coef  = (1.0f / ratio - 1.0f) / knee;
    const float C0    = -knee * Tthr * LOG2E;

    const float a4    = (alpha * alpha) * (alpha * alpha);
    const float a256  = powiu(a4, 64u);
    const float A1024 = powiu(a256, 4u);

    const long  base = (long)n * 2 * LLEN + (long)chunk * CHUNK;
    const float* x0 = x + base;
    const float* x1 = x0 + LLEN;
    const int woff = wid * 1024;          // wave segment offset in chunk

    __shared__ float wtB[NW], wtP[NW];
    __shared__ float carry_s;

    // ---- phase 1: own-tile loads ----
    float4 xa[4], xb[4];
    {
        const float4* p0 = reinterpret_cast<const float4*>(x0 + woff);
        const float4* p1 = reinterpret_cast<const float4*>(x1 + woff);
        #pragma unroll
        for (int q = 0; q < 4; ++q) {
            xa[q] = p0[q * 64 + lane];
            xb[q] = p1[q * 64 + lane];
        }
    }

    // ---- phase 2: own-side compute (b, rt, 4 interleaved wave scans) ----
    float b[4][4];
    #pragma unroll
    for (int q = 0; q < 4; ++q) {
        float4 a = xa[q], c = xb[q];
        b[q][0] = omah * fmaf(a.x, a.x, c.x * c.x);
        b[q][1] = omah * fmaf(a.y, a.y, c.y * c.y);
        b[q][2] = omah * fmaf(a.z, a.z, c.z * c.z);
        b[q][3] = omah * fmaf(a.w, a.w, c.w * c.w);
    }

    float rt[4];
    #pragma unroll
    for (int q = 0; q < 4; ++q) {
        float s = b[q][0];
        s = fmaf(alpha, s, b[q][1]);
        s = fmaf(alpha, s, b[q][2]);
        s = fmaf(alpha, s, b[q][3]);
        rt[q] = s;
    }

    float v0 = rt[0], v1 = rt[1], v2 = rt[2], v3 = rt[3];
    float g = a4;
    #pragma unroll
    for (int off = 1; off < 64; off <<= 1) {
        float y0 = __shfl_up(v0, off, 64);
        float y1 = __shfl_up(v1, off, 64);
        float y2 = __shfl_up(v2, off, 64);
        float y3 = __shfl_up(v3, off, 64);
        if (lane >= off) {
            v0 = fmaf(g, y0, v0); v1 = fmaf(g, y1, v1);
            v2 = fmaf(g, y2, v2); v3 = fmaf(g, y3, v3);
        }
        g *= g;
    }
    float Ex[4];
    Ex[0] = __shfl_up(v0, 1, 64); Ex[1] = __shfl_up(v1, 1, 64);
    Ex[2] = __shfl_up(v2, 1, 64); Ex[3] = __shfl_up(v3, 1, 64);
    if (lane == 0) { Ex[0] = Ex[1] = Ex[2] = Ex[3] = 0.0f; }
    float S[4];
    S[0] = __shfl(v0, 63, 64); S[1] = __shfl(v1, 63, 64);
    S[2] = __shfl(v2, 63, 64); S[3] = __shfl(v3, 63, 64);

    float W = S[0];
    W = fmaf(a256, W, S[1]); W = fmaf(a256, W, S[2]); W = fmaf(a256, W, S[3]);

    if (lane == 0) wtB[wid] = W;
    __syncthreads();

    float C;   // carry = T(c-1)
    if (A16K == 0.0f) {
        // ---- common path: publish own total, spin for predecessor's ----
        if (tid == 0) {
            if (chunk + 1 < NBLK) {      // has a consumer
                float Wblk = 0.0f;
                #pragma unroll
                for (int ww = 0; ww < NW; ++ww) Wblk = fmaf(A1024, Wblk, wtB[ww]);
                const uint64_t pk = (1ull << 32) | (uint64_t)__float_as_uint(Wblk);
                __hip_atomic_store(&P[n * NBLK + chunk], pk,
                                   __ATOMIC_RELEASE, __HIP_MEMORY_SCOPE_AGENT);
            }
            if (chunk == 0) {
                carry_s = 0.0f;
            } else {
                uint64_t e;
                for (;;) {
                    e = __hip_atomic_load(&P[n * NBLK + chunk - 1],
                                          __ATOMIC_ACQUIRE, __HIP_MEMORY_SCOPE_AGENT);
                    if (e >> 32) break;
                    __builtin_amdgcn_s_sleep(2);
                }
                carry_s = __uint_as_float((uint32_t)(e & 0xffffffffu));
            }
        }
        __syncthreads();
        C = carry_s;
    } else {
        // ---- rare exact path (alpha > 0.9947): local prev read ----
        const float sc = A16K * omah;
        float uw = 0.0f;
        if (chunk > 0) {
            const float4* r0 = reinterpret_cast<const float4*>(x0 - CHUNK + woff);
            const float4* r1 = reinterpret_cast<const float4*>(x1 - CHUNK + woff);
            float sq[4];
            #pragma unroll
            for (int q = 0; q < 4; ++q) {
                float4 ta = r0[q * 64 + lane], tc = r1[q * 64 + lane];
                float pl0 = fmaf(ta.x, ta.x, tc.x * tc.x);
                float pl1 = fmaf(ta.y, ta.y, tc.y * tc.y);
                float pl2 = fmaf(ta.z, ta.z, tc.z * tc.z);
                float pl3 = fmaf(ta.w, ta.w, tc.w * tc.w);
                float s = omah * pl0;
                s = fmaf(alpha, s, omah * pl1);
                s = fmaf(alpha, s, omah * pl2);
                s = fmaf(alpha, s, omah * pl3);
                sq[q] = s;
                b[q][0] -= sc * pl0; b[q][1] -= sc * pl1;
                b[q][2] -= sc * pl2; b[q][3] -= sc * pl3;
            }
            const float lw = powiu(a4, (unsigned)(63 - lane));
            float t0 = sq[0] * lw, t1 = sq[1] * lw, t2 = sq[2] * lw, t3 = sq[3] * lw;
            #pragma unroll
            for (int off = 32; off; off >>= 1) {
                t0 += __shfl_xor(t0, off, 64);
                t1 += __shfl_xor(t1, off, 64);
                t2 += __shfl_xor(t2, off, 64);
                t3 += __shfl_xor(t3, off, 64);
            }
            uw = t0;
            uw = fmaf(a256, uw, t1);
            uw = fmaf(a256, uw, t2);
            uw = fmaf(a256, uw, t3);
        }
        // recompute rt and scans with corrected b (exact)
        #pragma unroll
        for (int q = 0; q < 4; ++q) {
            float s = b[q][0];
            s = fmaf(alpha, s, b[q][1]);
            s = fmaf(alpha, s, b[q][2]);
            s = fmaf(alpha, s, b[q][3]);
            rt[q] = s;
        }
        v0 = rt[0]; v1 = rt[1]; v2 = rt[2]; v3 = rt[3];
        float g2 = a4;
        #pragma unroll
        for (int off = 1; off < 64; off <<= 1) {
            float y0 = __shfl_up(v0, off, 64);
            float y1 = __shfl_up(v1, off, 64);
            float y2 = __shfl_up(v2, off, 64);
            float y3 = __shfl_up(v3, off, 64);
            if (lane >= off) {
                v0 = fmaf(g2, y0, v0); v1 = fmaf(g2, y1, v1);
                v2 = fmaf(g2, y2, v2); v3 = fmaf(g2, y3, v3);
            }
            g2 *= g2;
        }
        Ex[0] = __shfl_up(v0, 1, 64); Ex[1] = __shfl_up(v1, 1, 64);
        Ex[2] = __shfl_up(v2, 1, 64); Ex[3] = __shfl_up(v3, 1, 64);
        if (lane == 0) { Ex[0] = Ex[1] = Ex[2] = Ex[3] = 0.0f; }
        S[0] = __shfl(v0, 63, 64); S[1] = __shfl(v1, 63, 64);
        S[2] = __shfl(v2, 63, 64); S[3] = __shfl(v3, 63, 64);
        W = S[0];
        W = fmaf(a256, W, S[1]); W = fmaf(a256, W, S[2]); W = fmaf(a256, W, S[3]);
        if (lane == 0) { wtB[wid] = W; wtP[wid] = uw; }
        __syncthreads();
        C = 0.0f;
        #pragma unroll
        for (int ww = 0; ww < NW; ++ww) C = fmaf(A1024, C, wtP[ww]);
    }

    // exclusive prefix over preceding waves (own chunk)
    float wc = 0.0f;
    for (int ww = 0; ww < wid; ++ww) wc = fmaf(A1024, wc, wtB[ww]);

    const float e_wave = fmaf(powiu(A1024, (unsigned)wid), C, wc);
    const float a4l    = powiu(a4, (unsigned)lane);

    // ---- apply gain + non-temporal coalesced writes ----
    float cq = e_wave;                    // env prefix before run-block q
    floatx4* o0 = reinterpret_cast<floatx4*>(out + base + woff);
    floatx4* o1 = reinterpret_cast<floatx4*>(out + base + LLEN + woff);
    #pragma unroll
    for (int q = 0; q < 4; ++q) {
        float e = fmaf(a4l, cq, Ex[q]);   // env before this thread's run
        cq = fmaf(a256, cq, S[q]);        // advance to next run block
        float4 a = xa[q], c = xb[q];
        floatx4 oa, ob;
        const float* ia = reinterpret_cast<const float*>(&a);
        const float* ib = reinterpret_cast<const float*>(&c);
        #pragma unroll
        for (int m = 0; m < 4; ++m) {
            e = fmaf(alpha, e, b[q][m]);
            float t  = fmaf(knee, log2_hw(e + 1e-5f), C0);
            float u  = exp2_hw(t);
            float sp = log2_hw(1.0f + u);
            float gain = exp2_hw(coef * sp);
            oa[m] = gain * ia[m];
            ob[m] = gain * ib[m];
        }
        __builtin_nontemporal_store(oa, &o0[q * 64 + lane]);
        __builtin_nontemporal_store(ob, &o1[q * 64 + lane]);
    }
}

extern "C" void kernel_launch(void* const* d_in, const int* in_sizes, int n_in,
                              void* d_out, int out_size, void* d_ws, size_t ws_size,
                              hipStream_t stream) {
    const float* x  = (const float*)d_in[0];
    const float* za = (const float*)d_in[1];
    const float* lt = (const float*)d_in[2];
    const float* lr = (const float*)d_in[3];
    const float* lk = (const float*)d_in[4];
    float* out = (float*)d_out;
    uint64_t* P = (uint64_t*)d_ws;         // N*NBLK packed {ready|float} = 2 KB

    const int N = in_sizes[1];             // z_alpha is (N,1)
    // clear ready bits every call (d_ws is NOT re-poisoned between replays)
    hipMemsetAsync(P, 0, (size_t)N * NBLK * sizeof(uint64_t), stream);
    dim3 grid(NBLK, N), block(TPB);
    k_fused<<<grid, block, 0, stream>>>(x, za, lt, lr, lk, P, out);
}

// Round 16
// 15.368 us; speedup vs baseline: 1.5052x; 1.5052x over previous
//
#include <hip/hip_runtime.h>
#include <cmath>

#define LLEN 131072
#define IIRL 16384
#define CHUNK 16384           // == IIRL: window = exactly 1 prev chunk
#define NBLK (LLEN / CHUNK)   // 8 chunks per row
#define TPB 1024
#define NW (TPB / 64)         // 16 waves; 1024 elements per wave segment
// layout within a wave segment: elem i = 4*(64*q + lane) + m, q,m in [0,4)
// -> every float4 load/store is lane-contiguous (64 lanes x 16B = 1KiB)

typedef float floatx4 __attribute__((ext_vector_type(4)));

__device__ __forceinline__ float powiu(float b, unsigned e) {
    float r = 1.0f;
    while (e) { if (e & 1u) r *= b; b *= b; e >>= 1; }
    return r;
}

// native base-2 transcendentals (v_exp_f32 / v_log_f32)
__device__ __forceinline__ float exp2_hw(float x) { return __builtin_amdgcn_exp2f(x); }
__device__ __forceinline__ float log2_hw(float x) { return __builtin_amdgcn_logf(x); }

// ---------------------------------------------------------------------------
// R16 = R14 + underflow-pruned prev read.
// carry(c) = T(c-1) = Horner_{ww} wtP[ww] * A1024^(15-ww), A1024 = alpha^1024.
// For all realistic alpha (< ~0.9993) A1024 underflows to exactly 0.0f, so
// only wave 15's prev segment has a nonzero coefficient. Each wave skips its
// prev-tile load iff its coefficient is exactly 0 (and A16K==0) — publishing
// wtP=0, bit-identical to reading and multiplying by zero. Prev-read volume:
// 128KB -> 8KB per block (read amp 2.0x -> 1.06x).
// gain = (1+u)^coef, u = exp2(knee*log2(env+eps) + C0), C0 = -knee*T*log2e
// env[t] = a*env[t-1] + (1-a)*(ls[t] - a^16384*ls[t-16384]), ls = mean_c(x^2)
// ---------------------------------------------------------------------------
__global__ __launch_bounds__(TPB) void k_fused(
    const float* __restrict__ x, const float* __restrict__ za,
    const float* __restrict__ lt, const float* __restrict__ lr,
    const float* __restrict__ lk, float* __restrict__ out)
{
    // XCD-aware bijective swizzle: consecutive chunks of a row -> same XCD.
    const int d     = blockIdx.y * gridDim.x + blockIdx.x;
    const int per   = (gridDim.x * gridDim.y) >> 3;   // total % 8 == 0
    const int w     = (d & 7) * per + (d >> 3);
    const int chunk = w % NBLK, n = w / NBLK;

    const int tid = threadIdx.x, lane = tid & 63, wid = tid >> 6;

    const float alpha = 1.0f / (1.0f + __expf(-za[n]));
    const float omah  = 0.5f * (1.0f - alpha);
    const float A16K  = powiu(alpha, IIRL);   // 0 unless alpha > 0.9947
    const float LOG2E = 1.4426950408889634f;
    const float Tthr  = lt[n] - 6.0f;
    const float ratio = 1.0f + __expf(lr[n]);
    const float knee  = __expf(lk[n] - 1.0f);
    const float coef  = (1.0f / ratio - 1.0f) / knee;
    const float C0    = -knee * Tthr * LOG2E;

    const float a4    = (alpha * alpha) * (alpha * alpha);
    const float a256  = powiu(a4, 64u);
    const float A1024 = powiu(a256, 4u);

    const long  base = (long)n * 2 * LLEN + (long)chunk * CHUNK;
    const float* x0 = x + base;
    const float* x1 = x0 + LLEN;
    const int woff = wid * 1024;          // wave segment offset in chunk

    // ---- phase 1: own-tile loads ----
    float4 xa[4], xb[4];
    {
        const float4* p0 = reinterpret_cast<const float4*>(x0 + woff);
        const float4* p1 = reinterpret_cast<const float4*>(x1 + woff);
        #pragma unroll
        for (int q = 0; q < 4; ++q) {
            xa[q] = p0[q * 64 + lane];
            xb[q] = p1[q * 64 + lane];
        }
    }

    // ---- phase 2: own-side compute (b, rt, 4 interleaved wave scans) ----
    float b[4][4];
    #pragma unroll
    for (int q = 0; q < 4; ++q) {
        float4 a = xa[q], c = xb[q];
        b[q][0] = omah * fmaf(a.x, a.x, c.x * c.x);
        b[q][1] = omah * fmaf(a.y, a.y, c.y * c.y);
        b[q][2] = omah * fmaf(a.z, a.z, c.z * c.z);
        b[q][3] = omah * fmaf(a.w, a.w, c.w * c.w);
    }

    float rt[4];
    #pragma unroll
    for (int q = 0; q < 4; ++q) {
        float s = b[q][0];
        s = fmaf(alpha, s, b[q][1]);
        s = fmaf(alpha, s, b[q][2]);
        s = fmaf(alpha, s, b[q][3]);
        rt[q] = s;
    }

    float v0 = rt[0], v1 = rt[1], v2 = rt[2], v3 = rt[3];
    float g = a4;
    #pragma unroll
    for (int off = 1; off < 64; off <<= 1) {
        float y0 = __shfl_up(v0, off, 64);
        float y1 = __shfl_up(v1, off, 64);
        float y2 = __shfl_up(v2, off, 64);
        float y3 = __shfl_up(v3, off, 64);
        if (lane >= off) {
            v0 = fmaf(g, y0, v0); v1 = fmaf(g, y1, v1);
            v2 = fmaf(g, y2, v2); v3 = fmaf(g, y3, v3);
        }
        g *= g;
    }
    float Ex[4];
    Ex[0] = __shfl_up(v0, 1, 64); Ex[1] = __shfl_up(v1, 1, 64);
    Ex[2] = __shfl_up(v2, 1, 64); Ex[3] = __shfl_up(v3, 1, 64);
    if (lane == 0) { Ex[0] = Ex[1] = Ex[2] = Ex[3] = 0.0f; }
    float S[4];
    S[0] = __shfl(v0, 63, 64); S[1] = __shfl(v1, 63, 64);
    S[2] = __shfl(v2, 63, 64); S[3] = __shfl(v3, 63, 64);

    // wave total (1024 elems): Horner over run blocks
    float W = S[0];
    W = fmaf(a256, W, S[1]); W = fmaf(a256, W, S[2]); W = fmaf(a256, W, S[3]);

    // ---- phase 3: prev-tile loads (underflow-pruned) + sq + tail ----
    // this wave's coefficient in the T(c-1) Horner combine:
    const float sA = powiu(A1024, (unsigned)(15 - wid));
    const bool readPrev = (chunk > 0) && ((sA != 0.0f) || (A16K != 0.0f));
    const float sc = A16K * omah;
    float uw = 0.0f;
    if (readPrev) {
        float4 pa[4], pb[4];
        const float4* r0 = reinterpret_cast<const float4*>(x0 - CHUNK + woff);
        const float4* r1 = reinterpret_cast<const float4*>(x1 - CHUNK + woff);
        #pragma unroll
        for (int q = 0; q < 4; ++q) {
            pa[q] = r0[q * 64 + lane];
            pb[q] = r1[q * 64 + lane];
        }
        float sq[4];
        #pragma unroll
        for (int q = 0; q < 4; ++q) {
            float4 ta = pa[q], tc = pb[q];
            float pl0 = fmaf(ta.x, ta.x, tc.x * tc.x);
            float pl1 = fmaf(ta.y, ta.y, tc.y * tc.y);
            float pl2 = fmaf(ta.z, ta.z, tc.z * tc.z);
            float pl3 = fmaf(ta.w, ta.w, tc.w * tc.w);
            float s = omah * pl0;
            s = fmaf(alpha, s, omah * pl1);
            s = fmaf(alpha, s, omah * pl2);
            s = fmaf(alpha, s, omah * pl3);
            sq[q] = s;
            if (A16K != 0.0f) {               // pathological-alpha exact tail
                b[q][0] -= sc * pl0; b[q][1] -= sc * pl1;
                b[q][2] -= sc * pl2; b[q][3] -= sc * pl3;
            }
        }
        const float lw = powiu(a4, (unsigned)(63 - lane));
        float t0 = sq[0] * lw, t1 = sq[1] * lw, t2 = sq[2] * lw, t3 = sq[3] * lw;
        #pragma unroll
        for (int off = 32; off; off >>= 1) {
            t0 += __shfl_xor(t0, off, 64);
            t1 += __shfl_xor(t1, off, 64);
            t2 += __shfl_xor(t2, off, 64);
            t3 += __shfl_xor(t3, off, 64);
        }
        uw = t0;
        uw = fmaf(a256, uw, t1);
        uw = fmaf(a256, uw, t2);
        uw = fmaf(a256, uw, t3);
    }
    // rare exact-tail path (alpha > 0.9947): b changed after the scan above,
    // so redo rt + scans with the corrected b (block-uniform, ~never taken)
    if (A16K != 0.0f && chunk > 0) {
        #pragma unroll
        for (int q = 0; q < 4; ++q) {
            float s = b[q][0];
            s = fmaf(alpha, s, b[q][1]);
            s = fmaf(alpha, s, b[q][2]);
            s = fmaf(alpha, s, b[q][3]);
            rt[q] = s;
        }
        v0 = rt[0]; v1 = rt[1]; v2 = rt[2]; v3 = rt[3];
        float g2 = a4;
        #pragma unroll
        for (int off = 1; off < 64; off <<= 1) {
            float y0 = __shfl_up(v0, off, 64);
            float y1 = __shfl_up(v1, off, 64);
            float y2 = __shfl_up(v2, off, 64);
            float y3 = __shfl_up(v3, off, 64);
            if (lane >= off) {
                v0 = fmaf(g2, y0, v0); v1 = fmaf(g2, y1, v1);
                v2 = fmaf(g2, y2, v2); v3 = fmaf(g2, y3, v3);
            }
            g2 *= g2;
        }
        Ex[0] = __shfl_up(v0, 1, 64); Ex[1] = __shfl_up(v1, 1, 64);
        Ex[2] = __shfl_up(v2, 1, 64); Ex[3] = __shfl_up(v3, 1, 64);
        if (lane == 0) { Ex[0] = Ex[1] = Ex[2] = Ex[3] = 0.0f; }
        S[0] = __shfl(v0, 63, 64); S[1] = __shfl(v1, 63, 64);
        S[2] = __shfl(v2, 63, 64); S[3] = __shfl(v3, 63, 64);
        W = S[0];
        W = fmaf(a256, W, S[1]); W = fmaf(a256, W, S[2]); W = fmaf(a256, W, S[3]);
    }

    __shared__ float wtB[NW], wtP[NW];
    if (lane == 0) { wtB[wid] = W; wtP[wid] = uw; }
    __syncthreads();

    // block-level: carry T(c-1) + exclusive prefix over waves (own chunk)
    float C = 0.0f;
    #pragma unroll
    for (int ww = 0; ww < NW; ++ww) C = fmaf(A1024, C, wtP[ww]);
    float wc = 0.0f;
    for (int ww = 0; ww < wid; ++ww) wc = fmaf(A1024, wc, wtB[ww]);

    const float e_wave = fmaf(powiu(A1024, (unsigned)wid), C, wc);
    const float a4l    = powiu(a4, (unsigned)lane);

    // ---- apply gain + non-temporal coalesced writes ----
    float cq = e_wave;                    // env prefix before run-block q
    floatx4* o0 = reinterpret_cast<floatx4*>(out + base + woff);
    floatx4* o1 = reinterpret_cast<floatx4*>(out + base + LLEN + woff);
    #pragma unroll
    for (int q = 0; q < 4; ++q) {
        float e = fmaf(a4l, cq, Ex[q]);   // env before this thread's run
        cq = fmaf(a256, cq, S[q]);        // advance to next run block
        float4 a = xa[q], c = xb[q];
        floatx4 oa, ob;
        const float* ia = reinterpret_cast<const float*>(&a);
        const float* ib = reinterpret_cast<const float*>(&c);
        #pragma unroll
        for (int m = 0; m < 4; ++m) {
            e = fmaf(alpha, e, b[q][m]);
            float t  = fmaf(knee, log2_hw(e + 1e-5f), C0);
            float u  = exp2_hw(t);
            float sp = log2_hw(1.0f + u);
            float gain = exp2_hw(coef * sp);
            oa[m] = gain * ia[m];
            ob[m] = gain * ib[m];
        }
        __builtin_nontemporal_store(oa, &o0[q * 64 + lane]);
        __builtin_nontemporal_store(ob, &o1[q * 64 + lane]);
    }
}

extern "C" void kernel_launch(void* const* d_in, const int* in_sizes, int n_in,
                              void* d_out, int out_size, void* d_ws, size_t ws_size,
                              hipStream_t stream) {
    const float* x  = (const float*)d_in[0];
    const float* za = (const float*)d_in[1];
    const float* lt = (const float*)d_in[2];
    const float* lr = (const float*)d_in[3];
    const float* lk = (const float*)d_in[4];
    float* out = (float*)d_out;

    const int N = in_sizes[1];             // z_alpha is (N,1)
    dim3 grid(NBLK, N), block(TPB);
    k_fused<<<grid, block, 0, stream>>>(x, za, lt, lr, lk, out);
}

// Round 17
// 13.644 us; speedup vs baseline: 1.6955x; 1.1264x over previous
//
#include <hip/hip_runtime.h>
#include <cmath>

#define LLEN 131072
#define IIRL 16384
#define SEG  1024             // one wave owns one segment, fully independent
#define SPR  (LLEN / SEG)     // 128 segments per row
#define TPB  256
#define WPB  (TPB / 64)       // 4 waves per block
// layout within a segment: elem i = 4*(64*q + lane) + m, q,m in [0,4)
// -> every float4 load/store is lane-contiguous (64 lanes x 16B = 1KiB)

typedef float floatx4 __attribute__((ext_vector_type(4)));

__device__ __forceinline__ float powiu(float b, unsigned e) {
    float r = 1.0f;
    while (e) { if (e & 1u) r *= b; b *= b; e >>= 1; }
    return r;
}

// native base-2 transcendentals (v_exp_f32 / v_log_f32)
__device__ __forceinline__ float exp2_hw(float x) { return __builtin_amdgcn_exp2f(x); }
__device__ __forceinline__ float log2_hw(float x) { return __builtin_amdgcn_logf(x); }

// weighted total of one 1024-sample segment (zero-init chain):
//   T = sum_i alpha^(1023-i) * omah*(x0[i]^2 + x1[i]^2)
__device__ __forceinline__ float seg_total(
    const float4* __restrict__ r0, const float4* __restrict__ r1,
    int lane, float alpha, float omah, float a4, float a256)
{
    float4 pa[4], pb[4];
    #pragma unroll
    for (int q = 0; q < 4; ++q) { pa[q] = r0[q*64+lane]; pb[q] = r1[q*64+lane]; }
    float u = 0.0f;
    #pragma unroll
    for (int q = 0; q < 4; ++q) {
        float4 ta = pa[q], tc = pb[q];
        float s = omah * fmaf(ta.x, ta.x, tc.x * tc.x);
        s = fmaf(alpha, s, omah * fmaf(ta.y, ta.y, tc.y * tc.y));
        s = fmaf(alpha, s, omah * fmaf(ta.z, ta.z, tc.z * tc.z));
        s = fmaf(alpha, s, omah * fmaf(ta.w, ta.w, tc.w * tc.w));
        u = fmaf(a256, u, s);              // Horner over q-groups
    }
    u *= powiu(a4, (unsigned)(63 - lane)); // lane weight
    #pragma unroll
    for (int off = 32; off; off >>= 1) u += __shfl_xor(u, off, 64);
    return u;
}

// ---------------------------------------------------------------------------
// R17: fully wave-independent (no LDS, no __syncthreads, no block coupling).
// carry(g) = env[seg_start-1] = T(g-1): all deeper segment totals carry
// Horner coefficients A1024^k = (alpha^1024)^k which underflow to exactly
// 0.0f for realistic alpha — identical arithmetic to R14/R16's block combine.
// Rare alpha paths (A1024!=0: deep carry loop; A16K!=0: exact b-tail from
// seg g-16, applied BEFORE the scan) stay exact and wave-uniform.
// Waves free-run: reads/scan/writes from 16 waves/CU overlap continuously.
// gain = (1+u)^coef, u = exp2(knee*log2(env+eps) + C0), C0 = -knee*T*log2e
// env[t] = a*env[t-1] + (1-a)*(ls[t] - a^16384*ls[t-16384]), ls = mean_c(x^2)
// ---------------------------------------------------------------------------
__global__ __launch_bounds__(TPB) void k_fused(
    const float* __restrict__ x, const float* __restrict__ za,
    const float* __restrict__ lt, const float* __restrict__ lr,
    const float* __restrict__ lk, float* __restrict__ out)
{
    const int lane = threadIdx.x & 63, wid = threadIdx.x >> 6;
    // XCD-aware bijective swizzle: consecutive segments of a row -> same XCD
    const int per = gridDim.x >> 3;                   // gridDim.x % 8 == 0
    const int bsw = (blockIdx.x & 7) * per + (blockIdx.x >> 3);
    const int g   = bsw * WPB + wid;                  // global segment id
    const int n   = g >> 7, s = g & (SPR - 1);        // row, segment-in-row

    const float alpha = 1.0f / (1.0f + __expf(-za[n]));
    const float omah  = 0.5f * (1.0f - alpha);
    const float A16K  = powiu(alpha, IIRL);   // 0 unless alpha > 0.9947
    const float LOG2E = 1.4426950408889634f;
    const float Tthr  = lt[n] - 6.0f;
    const float ratio = 1.0f + __expf(lr[n]);
    const float knee  = __expf(lk[n] - 1.0f);
    const float coef  = (1.0f / ratio - 1.0f) / knee;
    const float C0    = -knee * Tthr * LOG2E;

    const float a4    = (alpha * alpha) * (alpha * alpha);
    const float a256  = powiu(a4, 64u);
    const float A1024 = powiu(a256, 4u);      // 0 unless alpha > ~0.9993

    const long base = (long)n * 2 * LLEN + (long)s * SEG;
    const float* x0 = x + base;
    const float* x1 = x0 + LLEN;

    // ---- own-segment loads (issued first, max MLP) ----
    float4 xa[4], xb[4];
    {
        const float4* p0 = reinterpret_cast<const float4*>(x0);
        const float4* p1 = reinterpret_cast<const float4*>(x1);
        #pragma unroll
        for (int q = 0; q < 4; ++q) {
            xa[q] = p0[q * 64 + lane];
            xb[q] = p1[q * 64 + lane];
        }
    }

    // ---- carry = T(g-1) (prev-seg loads overlap own-side compute) ----
    float carry = 0.0f;
    if (s > 0) {
        carry = seg_total(reinterpret_cast<const float4*>(x0 - SEG),
                          reinterpret_cast<const float4*>(x1 - SEG),
                          lane, alpha, omah, a4, a256);
    }

    // ---- b values (recurrence input) ----
    float b[4][4];
    #pragma unroll
    for (int q = 0; q < 4; ++q) {
        float4 a = xa[q], c = xb[q];
        b[q][0] = omah * fmaf(a.x, a.x, c.x * c.x);
        b[q][1] = omah * fmaf(a.y, a.y, c.y * c.y);
        b[q][2] = omah * fmaf(a.z, a.z, c.z * c.z);
        b[q][3] = omah * fmaf(a.w, a.w, c.w * c.w);
    }

    // ---- rare exact paths (wave-uniform; alpha extreme) ----
    if (A16K != 0.0f && s >= 16) {            // exact truncation tail
        const float4* t0p = reinterpret_cast<const float4*>(x0 - IIRL);
        const float4* t1p = reinterpret_cast<const float4*>(x1 - IIRL);
        const float sc = A16K * omah;
        #pragma unroll
        for (int q = 0; q < 4; ++q) {
            float4 ta = t0p[q * 64 + lane], tc = t1p[q * 64 + lane];
            b[q][0] -= sc * fmaf(ta.x, ta.x, tc.x * tc.x);
            b[q][1] -= sc * fmaf(ta.y, ta.y, tc.y * tc.y);
            b[q][2] -= sc * fmaf(ta.z, ta.z, tc.z * tc.z);
            b[q][3] -= sc * fmaf(ta.w, ta.w, tc.w * tc.w);
        }
    }
    if (A1024 != 0.0f && s > 1) {             // deep carry (alpha > ~0.9993)
        float wk = A1024;
        for (int k = 2; k <= 16; ++k) {
            if (s - k < 0 || wk == 0.0f) break;
            float Tk = seg_total(
                reinterpret_cast<const float4*>(x0 - (long)k * SEG),
                reinterpret_cast<const float4*>(x1 - (long)k * SEG),
                lane, alpha, omah, a4, a256);
            carry = fmaf(wk, Tk, carry);
            wk *= A1024;
        }
    }

    // ---- per-thread run totals (4 independent chains) ----
    float rt[4];
    #pragma unroll
    for (int q = 0; q < 4; ++q) {
        float sv = b[q][0];
        sv = fmaf(alpha, sv, b[q][1]);
        sv = fmaf(alpha, sv, b[q][2]);
        sv = fmaf(alpha, sv, b[q][3]);
        rt[q] = sv;
    }

    // ---- 4 interleaved wave scans over lanes (ratio a^4) ----
    float v0 = rt[0], v1 = rt[1], v2 = rt[2], v3 = rt[3];
    float gg = a4;
    #pragma unroll
    for (int off = 1; off < 64; off <<= 1) {
        float y0 = __shfl_up(v0, off, 64);
        float y1 = __shfl_up(v1, off, 64);
        float y2 = __shfl_up(v2, off, 64);
        float y3 = __shfl_up(v3, off, 64);
        if (lane >= off) {
            v0 = fmaf(gg, y0, v0); v1 = fmaf(gg, y1, v1);
            v2 = fmaf(gg, y2, v2); v3 = fmaf(gg, y3, v3);
        }
        gg *= gg;
    }
    float Ex[4];
    Ex[0] = __shfl_up(v0, 1, 64); Ex[1] = __shfl_up(v1, 1, 64);
    Ex[2] = __shfl_up(v2, 1, 64); Ex[3] = __shfl_up(v3, 1, 64);
    if (lane == 0) { Ex[0] = Ex[1] = Ex[2] = Ex[3] = 0.0f; }
    float S[4];
    S[0] = __shfl(v0, 63, 64); S[1] = __shfl(v1, 63, 64);
    S[2] = __shfl(v2, 63, 64); S[3] = __shfl(v3, 63, 64);

    const float a4l = powiu(a4, (unsigned)lane);

    // ---- apply gain + non-temporal coalesced writes ----
    float cq = carry;                     // env prefix before run-block q
    floatx4* o0 = reinterpret_cast<floatx4*>(out + base);
    floatx4* o1 = reinterpret_cast<floatx4*>(out + base + LLEN);
    #pragma unroll
    for (int q = 0; q < 4; ++q) {
        float e = fmaf(a4l, cq, Ex[q]);   // env before this thread's run
        cq = fmaf(a256, cq, S[q]);        // advance to next run block
        float4 a = xa[q], c = xb[q];
        floatx4 oa, ob;
        const float* ia = reinterpret_cast<const float*>(&a);
        const float* ib = reinterpret_cast<const float*>(&c);
        #pragma unroll
        for (int m = 0; m < 4; ++m) {
            e = fmaf(alpha, e, b[q][m]);
            float t  = fmaf(knee, log2_hw(e + 1e-5f), C0);
            float u  = exp2_hw(t);
            float sp = log2_hw(1.0f + u);
            float gain = exp2_hw(coef * sp);
            oa[m] = gain * ia[m];
            ob[m] = gain * ib[m];
        }
        __builtin_nontemporal_store(oa, &o0[q * 64 + lane]);
        __builtin_nontemporal_store(ob, &o1[q * 64 + lane]);
    }
}

extern "C" void kernel_launch(void* const* d_in, const int* in_sizes, int n_in,
                              void* d_out, int out_size, void* d_ws, size_t ws_size,
                              hipStream_t stream) {
    const float* x  = (const float*)d_in[0];
    const float* za = (const float*)d_in[1];
    const float* lt = (const float*)d_in[2];
    const float* lr = (const float*)d_in[3];
    const float* lk = (const float*)d_in[4];
    float* out = (float*)d_out;

    const int N = in_sizes[1];             // z_alpha is (N,1)
    const int nblk = N * SPR / WPB;        // one wave per segment (N*32 blocks)
    k_fused<<<dim3(nblk), dim3(TPB), 0, stream>>>(x, za, lt, lr, lk, out);
}